// Round 7
// baseline (1058.331 us; speedup 1.0000x reference)
//
#include <hip/hip_runtime.h>
#include <cstddef>

static constexpr int B = 32;
static constexpr int N = 1024;
static constexpr int BPB = 16;    // blocks per batch
static constexpr int CTRS = 16;   // u32 stride per batch counter (64 B)

// ---------------------------------------------------------------------------
// 5-bit bit-reversal (involution): lane -> scalar index after log-reduce
// ---------------------------------------------------------------------------
__device__ __forceinline__ int rev5(int l) {
    return ((l & 1) << 4) | ((l & 2) << 2) | (l & 4) | ((l & 8) >> 2) | ((l & 16) >> 4);
}

// ---------------------------------------------------------------------------
// Logarithmic multi-scalar reduce [HW-verified r2/r4/r5 outputs 0-2]
// ---------------------------------------------------------------------------
__device__ __forceinline__ float reduce32(float (&v)[32]) {
    const int lane = (int)(threadIdx.x & 63);
    float a[16], b[8], c[4], d[2];
#pragma unroll
    for (int i = 0; i < 16; ++i) {
        float lo = v[i]      + __shfl_xor(v[i],      1, 64);
        float hi = v[i + 16] + __shfl_xor(v[i + 16], 1, 64);
        a[i] = (lane & 1) ? hi : lo;
    }
#pragma unroll
    for (int i = 0; i < 8; ++i) {
        float lo = a[i]     + __shfl_xor(a[i],     2, 64);
        float hi = a[i + 8] + __shfl_xor(a[i + 8], 2, 64);
        b[i] = (lane & 2) ? hi : lo;
    }
#pragma unroll
    for (int i = 0; i < 4; ++i) {
        float lo = b[i]     + __shfl_xor(b[i],     4, 64);
        float hi = b[i + 4] + __shfl_xor(b[i + 4], 4, 64);
        c[i] = (lane & 4) ? hi : lo;
    }
#pragma unroll
    for (int i = 0; i < 2; ++i) {
        float lo = c[i]     + __shfl_xor(c[i],     8, 64);
        float hi = c[i + 2] + __shfl_xor(c[i + 2], 8, 64);
        d[i] = (lane & 8) ? hi : lo;
    }
    {
        float lo = d[0] + __shfl_xor(d[0], 16, 64);
        float hi = d[1] + __shfl_xor(d[1], 16, 64);
        float e  = (lane & 16) ? hi : lo;
        e += __shfl_xor(e, 32, 64);
        return e;
    }
}

// ---------------------------------------------------------------------------
// Per-batch barrier, agent scope. [HW-verified protocol for ws-mediated
// cross-block communication, r2/r4/r5]. REGULAR launch; co-residency
// guaranteed: grid 512 <= 4 blocks/CU x 256 CU capacity (LDS 28KB, VGPR<=128).
// ---------------------------------------------------------------------------
__device__ __forceinline__ void batch_barrier(unsigned* ctr, unsigned target) {
    __syncthreads();
    if (threadIdx.x == 0) {
        __hip_atomic_fetch_add(ctr, 1u, __ATOMIC_RELEASE, __HIP_MEMORY_SCOPE_AGENT);
        while (__hip_atomic_load(ctr, __ATOMIC_ACQUIRE, __HIP_MEMORY_SCOPE_AGENT) < target)
            __builtin_amdgcn_s_sleep(2);
    }
    __syncthreads();
}

// ---------------------------------------------------------------------------
// Shared m-loop: 4 half-blocks of 16 rows (4 rows/wave) = 64 rows/block,
// dot vs yds[FOUT][N], log-reduce, tanh, write xout[b][FOUT][N].
// ---------------------------------------------------------------------------
template <int FOUT>
__device__ __forceinline__ void adj_rows_tanh_write(const float* __restrict__ adjb,
                                                    const float* __restrict__ yds,
                                                    float* __restrict__ xoutb, int n0) {
    const int wave = (int)(threadIdx.x >> 6);
    const int lane = (int)(threadIdx.x & 63);
    for (int half = 0; half < 4; ++half) {
        const int nb = n0 + half * 16 + (wave << 2);
        float v[32];
#pragma unroll
        for (int i = 0; i < 32; ++i) v[i] = 0.f;
#pragma unroll
        for (int k = 0; k < 4; ++k) {
            const int m = (k << 8) + (lane << 2);
            float4 a4[4];
#pragma unroll
            for (int r = 0; r < 4; ++r)
                a4[r] = *(const float4*)(adjb + (size_t)(nb + r) * N + m);
#pragma unroll
            for (int f = 0; f < FOUT; ++f) {
                const float4 yv = *(const float4*)&yds[f * N + m];
#pragma unroll
                for (int r = 0; r < 4; ++r)
                    v[r * 8 + f] += a4[r].x * yv.x + a4[r].y * yv.y +
                                    a4[r].z * yv.z + a4[r].w * yv.w;
            }
        }
        const float tot = reduce32(v);
        const int s = rev5(lane & 31);
        const int r = s >> 3, f = s & 7;
        if (lane < 32 && f < FOUT)
            xoutb[(size_t)f * N + nb + r] = tanhf(tot);
    }
}

// Generic layer: xin [b][FIN][N] in ws  [HW-verified]
template <int FIN, int FOUT>
__device__ __forceinline__ void do_layer(const float* __restrict__ xin,
                                         const float* __restrict__ adj,
                                         const float* __restrict__ W,
                                         float* __restrict__ xout,
                                         float* __restrict__ yds, int b, int n0) {
    float w[FIN][FOUT];
#pragma unroll
    for (int fi = 0; fi < FIN; ++fi)
#pragma unroll
        for (int f = 0; f < FOUT; ++f) w[fi][f] = W[fi * FOUT + f];

    {
        const int m4 = (int)(threadIdx.x << 2);
        const float* xbp = xin + (size_t)b * FIN * N + m4;
        float4 xv[FIN];
#pragma unroll
        for (int fi = 0; fi < FIN; ++fi)
            xv[fi] = *(const float4*)(xbp + fi * N);
#pragma unroll
        for (int f = 0; f < FOUT; ++f) {
            float4 a = make_float4(0.f, 0.f, 0.f, 0.f);
#pragma unroll
            for (int fi = 0; fi < FIN; ++fi) {
                a.x += xv[fi].x * w[fi][f];
                a.y += xv[fi].y * w[fi][f];
                a.z += xv[fi].z * w[fi][f];
                a.w += xv[fi].w * w[fi][f];
            }
            *(float4*)&yds[f * N + m4] = a;
        }
    }
    __syncthreads();
    adj_rows_tanh_write<FOUT>(adj + (size_t)b * N * N, yds,
                              xout + (size_t)b * FOUT * N, n0);
}

// Layer 1: reads X [B][N][8] directly  [HW-verified]
__device__ __forceinline__ void do_layer1(const float* __restrict__ X,
                                          const float* __restrict__ adj,
                                          const float* __restrict__ W,
                                          float* __restrict__ xout,
                                          float* __restrict__ yds, int b, int n0) {
    float w[8][7];
#pragma unroll
    for (int fi = 0; fi < 8; ++fi)
#pragma unroll
        for (int f = 0; f < 7; ++f) w[fi][f] = W[fi * 7 + f];

    {
        const int m4 = (int)(threadIdx.x << 2);
        const float* xp = X + (size_t)b * 8192 + (size_t)m4 * 8;
        float4 lo[4], hi[4];
#pragma unroll
        for (int j = 0; j < 4; ++j) {
            lo[j] = *(const float4*)(xp + j * 8);
            hi[j] = *(const float4*)(xp + j * 8 + 4);
        }
#pragma unroll
        for (int f = 0; f < 7; ++f) {
            float4 a;
            a.x = lo[0].x * w[0][f] + lo[0].y * w[1][f] + lo[0].z * w[2][f] + lo[0].w * w[3][f]
                + hi[0].x * w[4][f] + hi[0].y * w[5][f] + hi[0].z * w[6][f] + hi[0].w * w[7][f];
            a.y = lo[1].x * w[0][f] + lo[1].y * w[1][f] + lo[1].z * w[2][f] + lo[1].w * w[3][f]
                + hi[1].x * w[4][f] + hi[1].y * w[5][f] + hi[1].z * w[6][f] + hi[1].w * w[7][f];
            a.z = lo[2].x * w[0][f] + lo[2].y * w[1][f] + lo[2].z * w[2][f] + lo[2].w * w[3][f]
                + hi[2].x * w[4][f] + hi[2].y * w[5][f] + hi[2].z * w[6][f] + hi[2].w * w[7][f];
            a.w = lo[3].x * w[0][f] + lo[3].y * w[1][f] + lo[3].z * w[2][f] + lo[3].w * w[3][f]
                + hi[3].x * w[4][f] + hi[3].y * w[5][f] + hi[3].z * w[6][f] + hi[3].w * w[7][f];
            *(float4*)&yds[f * N + m4] = a;
        }
    }
    __syncthreads();
    adj_rows_tanh_write<7>(adj + (size_t)b * N * N, yds,
                           xout + (size_t)b * 7 * N, n0);
}

// mu/lv heads + reparameterization. [HW-verified r2/r4/r5]
__device__ __forceinline__ void do_muvl(const float* __restrict__ xin,
                                        const float* __restrict__ adj,
                                        const float* __restrict__ eps,
                                        const float* __restrict__ Wmu,
                                        const float* __restrict__ Wlv,
                                        float* __restrict__ out,
                                        float* __restrict__ yds, int b, int n0) {
    const float wm0 = Wmu[0], wm1 = Wmu[1];
    const float wl0 = Wlv[0], wl1 = Wlv[1];
    {
        const int m4 = (int)(threadIdx.x << 2);
        const float* xp = xin + (size_t)b * 2 * N;
        float4 x0 = *(const float4*)(xp + m4);
        float4 x1 = *(const float4*)(xp + N + m4);
        float4 ym, yl;
        ym.x = x0.x * wm0 + x1.x * wm1;  ym.y = x0.y * wm0 + x1.y * wm1;
        ym.z = x0.z * wm0 + x1.z * wm1;  ym.w = x0.w * wm0 + x1.w * wm1;
        yl.x = x0.x * wl0 + x1.x * wl1;  yl.y = x0.y * wl0 + x1.y * wl1;
        yl.z = x0.z * wl0 + x1.z * wl1;  yl.w = x0.w * wl0 + x1.w * wl1;
        *(float4*)&yds[m4]     = ym;
        *(float4*)&yds[N + m4] = yl;
    }
    __syncthreads();

    const int wave = (int)(threadIdx.x >> 6);
    const int lane = (int)(threadIdx.x & 63);
    const float* adjb = adj + (size_t)b * N * N;
    for (int half = 0; half < 4; ++half) {
        const int nb = n0 + half * 16 + (wave << 2);
        float v[32];
#pragma unroll
        for (int i = 0; i < 32; ++i) v[i] = 0.f;
#pragma unroll
        for (int k = 0; k < 4; ++k) {
            const int m = (k << 8) + (lane << 2);
            const float4 ym4 = *(const float4*)&yds[m];
            const float4 yl4 = *(const float4*)&yds[N + m];
#pragma unroll
            for (int r = 0; r < 4; ++r) {
                const float4 a4 = *(const float4*)(adjb + (size_t)(nb + r) * N + m);
                v[r * 8 + 0] += a4.x * ym4.x + a4.y * ym4.y + a4.z * ym4.z + a4.w * ym4.w;
                v[r * 8 + 1] += a4.x * yl4.x + a4.y * yl4.y + a4.z * yl4.z + a4.w * yl4.w;
            }
        }
        const float tot = reduce32(v);
        const float partner = __shfl_xor(tot, 16, 64);   // scalar s^1 (mu<->lv)
        const int s = rev5(lane & 31);
        if (lane < 32 && (s & 7) == 0) {
            const int r = s >> 3;
            const int n = nb + r;
            const float zm = tot, zlv = partner;
            const float e = eps[b * N + n];
            const float z = zm + e * expf(0.5f * zlv);
            out[b * N + n]         = z;
            out[32768 + b * N + n] = zm;
            out[65536 + b * N + n] = zlv;
        }
    }
}

// ---------------------------------------------------------------------------
// Fused stages 1-7. REGULAR launch, 512 blocks (16/batch, 64 rows/block).
// No hipLaunchCooperativeKernel: r6 showed coop launches are not reliably
// stream-ordered with subsequent dispatches on this stack.
// ---------------------------------------------------------------------------
__global__ __launch_bounds__(256, 4) void gvae_layers(
    const float* __restrict__ X, const float* __restrict__ adj,
    const float* __restrict__ eps,
    const float* __restrict__ W0, const float* __restrict__ W1,
    const float* __restrict__ W2, const float* __restrict__ W3,
    const float* __restrict__ W4, const float* __restrict__ W5,
    const float* __restrict__ Wmu, const float* __restrict__ Wlv,
    float* __restrict__ out, float* __restrict__ bufA,
    float* __restrict__ bufB, unsigned* __restrict__ ctrs) {
    __shared__ float yds[7 * N];          // 28 KB
    const int blk = (int)blockIdx.x;
    const int b   = blk >> 4;             // 16 blocks per batch
    const int n0  = (blk & 15) << 6;      // 64 rows per block
    unsigned* ctr = ctrs + b * CTRS;

    do_layer1(X, adj, W0, bufA, yds, b, n0);            batch_barrier(ctr, BPB * 1);
    do_layer<7, 6>(bufA, adj, W1, bufB, yds, b, n0);    batch_barrier(ctr, BPB * 2);
    do_layer<6, 5>(bufB, adj, W2, bufA, yds, b, n0);    batch_barrier(ctr, BPB * 3);
    do_layer<5, 4>(bufA, adj, W3, bufB, yds, b, n0);    batch_barrier(ctr, BPB * 4);
    do_layer<4, 3>(bufB, adj, W4, bufA, yds, b, n0);    batch_barrier(ctr, BPB * 5);
    do_layer<3, 2>(bufA, adj, W5, bufB, yds, b, n0);    batch_barrier(ctr, BPB * 6);
    do_muvl(bufB, adj, eps, Wmu, Wlv, out, yds, b, n0);
}

// ---------------------------------------------------------------------------
// adj_pred[b][n][m] = z[b][n] * z[b][m]  — round-1 kernel VERBATIM
// (HW-verified as a regular dispatch after regular dispatches).
// ---------------------------------------------------------------------------
__global__ __launch_bounds__(256) void adjpred_k(const float* __restrict__ z,
                                                 float* __restrict__ out) {
    const int b = blockIdx.x >> 10;
    const int n = blockIdx.x & 1023;
    const float zn = z[b * N + n];
    const int m4 = threadIdx.x << 2;
    const float4 zm4 = *(const float4*)(z + b * N + m4);
    float4 o;
    o.x = zn * zm4.x; o.y = zn * zm4.y; o.z = zn * zm4.z; o.w = zn * zm4.w;
    *(float4*)(out + ((size_t)b << 20) + ((size_t)n << 10) + m4) = o;
}

// ---------------------------------------------------------------------------
extern "C" void kernel_launch(void* const* d_in, const int* in_sizes, int n_in,
                              void* d_out, int out_size, void* d_ws, size_t ws_size,
                              hipStream_t stream) {
    const float* X   = (const float*)d_in[0];
    const float* adj = (const float*)d_in[1];
    const float* eps = (const float*)d_in[2];
    const float* W0  = (const float*)d_in[3];
    const float* W1  = (const float*)d_in[4];
    const float* W2  = (const float*)d_in[5];
    const float* W3  = (const float*)d_in[6];
    const float* W4  = (const float*)d_in[7];
    const float* W5  = (const float*)d_in[8];
    const float* Wmu = (const float*)d_in[9];
    const float* Wlv = (const float*)d_in[10];

    float* out  = (float*)d_out;
    float* bufA = (float*)d_ws;                       // <= 7*32*1024 floats
    float* bufB = bufA + (size_t)7 * B * N;           // <= 7*32*1024 floats
    unsigned* ctrs = (unsigned*)(bufB + (size_t)7 * B * N);  // 32*CTRS u32

    (void)hipMemsetAsync(ctrs, 0, B * CTRS * sizeof(unsigned), stream);

    gvae_layers<<<dim3(B * BPB), dim3(256), 0, stream>>>(
        X, adj, eps, W0, W1, W2, W3, W4, W5, Wmu, Wlv, out, bufA, bufB, ctrs);

    adjpred_k<<<B * N, 256, 0, stream>>>(out, out + 98304);
}

// Round 8
// 852.536 us; speedup vs baseline: 1.2414x; 1.2414x over previous
//
#include <hip/hip_runtime.h>
#include <cstddef>

static constexpr int B = 32;
static constexpr int N = 1024;
static constexpr int BPB = 16;    // blocks per batch
static constexpr int CTRS = 16;   // u32 stride per batch counter (64 B)

// ---------------------------------------------------------------------------
// 5-bit bit-reversal (involution): lane -> scalar index after log-reduce
// ---------------------------------------------------------------------------
__device__ __forceinline__ int rev5(int l) {
    return ((l & 1) << 4) | ((l & 2) << 2) | (l & 4) | ((l & 8) >> 2) | ((l & 16) >> 4);
}

// ---------------------------------------------------------------------------
// Logarithmic multi-scalar reduce [HW-verified r2/r4/r5/r7]
// ---------------------------------------------------------------------------
__device__ __forceinline__ float reduce32(float (&v)[32]) {
    const int lane = (int)(threadIdx.x & 63);
    float a[16], b[8], c[4], d[2];
#pragma unroll
    for (int i = 0; i < 16; ++i) {
        float lo = v[i]      + __shfl_xor(v[i],      1, 64);
        float hi = v[i + 16] + __shfl_xor(v[i + 16], 1, 64);
        a[i] = (lane & 1) ? hi : lo;
    }
#pragma unroll
    for (int i = 0; i < 8; ++i) {
        float lo = a[i]     + __shfl_xor(a[i],     2, 64);
        float hi = a[i + 8] + __shfl_xor(a[i + 8], 2, 64);
        b[i] = (lane & 2) ? hi : lo;
    }
#pragma unroll
    for (int i = 0; i < 4; ++i) {
        float lo = b[i]     + __shfl_xor(b[i],     4, 64);
        float hi = b[i + 4] + __shfl_xor(b[i + 4], 4, 64);
        c[i] = (lane & 4) ? hi : lo;
    }
#pragma unroll
    for (int i = 0; i < 2; ++i) {
        float lo = c[i]     + __shfl_xor(c[i],     8, 64);
        float hi = c[i + 2] + __shfl_xor(c[i + 2], 8, 64);
        d[i] = (lane & 8) ? hi : lo;
    }
    {
        float lo = d[0] + __shfl_xor(d[0], 16, 64);
        float hi = d[1] + __shfl_xor(d[1], 16, 64);
        float e  = (lane & 16) ? hi : lo;
        e += __shfl_xor(e, 32, 64);
        return e;
    }
}

// ---------------------------------------------------------------------------
// Per-batch barrier, agent scope. RELAXED spin (no per-iteration cache
// invalidate!) + ONE acquire load after the spin exits, pairing with the
// release-RMW. r7's acquire-in-spin variant invalidated L1/L2 every spin
// iteration -> invalidation storm: FETCH 1.66GB, WRITE 614MB, VALUBusy 3.4%.
// ---------------------------------------------------------------------------
__device__ __forceinline__ void batch_barrier(unsigned* ctr, unsigned target) {
    __syncthreads();
    if (threadIdx.x == 0) {
        __hip_atomic_fetch_add(ctr, 1u, __ATOMIC_RELEASE, __HIP_MEMORY_SCOPE_AGENT);
        while (__hip_atomic_load(ctr, __ATOMIC_RELAXED, __HIP_MEMORY_SCOPE_AGENT) < target)
            __builtin_amdgcn_s_sleep(2);
        (void)__hip_atomic_load(ctr, __ATOMIC_ACQUIRE, __HIP_MEMORY_SCOPE_AGENT);
    }
    __syncthreads();
}

// ---------------------------------------------------------------------------
// Shared m-loop: 4 half-blocks of 16 rows (4 rows/wave) = 64 rows/block,
// dot vs yds[FOUT][N], log-reduce, tanh, write xout[b][FOUT][N].
// ---------------------------------------------------------------------------
template <int FOUT>
__device__ __forceinline__ void adj_rows_tanh_write(const float* __restrict__ adjb,
                                                    const float* __restrict__ yds,
                                                    float* __restrict__ xoutb, int n0) {
    const int wave = (int)(threadIdx.x >> 6);
    const int lane = (int)(threadIdx.x & 63);
    for (int half = 0; half < 4; ++half) {
        const int nb = n0 + half * 16 + (wave << 2);
        float v[32];
#pragma unroll
        for (int i = 0; i < 32; ++i) v[i] = 0.f;
#pragma unroll
        for (int k = 0; k < 4; ++k) {
            const int m = (k << 8) + (lane << 2);
            float4 a4[4];
#pragma unroll
            for (int r = 0; r < 4; ++r)
                a4[r] = *(const float4*)(adjb + (size_t)(nb + r) * N + m);
#pragma unroll
            for (int f = 0; f < FOUT; ++f) {
                const float4 yv = *(const float4*)&yds[f * N + m];
#pragma unroll
                for (int r = 0; r < 4; ++r)
                    v[r * 8 + f] += a4[r].x * yv.x + a4[r].y * yv.y +
                                    a4[r].z * yv.z + a4[r].w * yv.w;
            }
        }
        const float tot = reduce32(v);
        const int s = rev5(lane & 31);
        const int r = s >> 3, f = s & 7;
        if (lane < 32 && f < FOUT)
            xoutb[(size_t)f * N + nb + r] = tanhf(tot);
    }
}

// Generic layer: xin [b][FIN][N] in ws  [HW-verified]
template <int FIN, int FOUT>
__device__ __forceinline__ void do_layer(const float* __restrict__ xin,
                                         const float* __restrict__ adj,
                                         const float* __restrict__ W,
                                         float* __restrict__ xout,
                                         float* __restrict__ yds, int b, int n0) {
    float w[FIN][FOUT];
#pragma unroll
    for (int fi = 0; fi < FIN; ++fi)
#pragma unroll
        for (int f = 0; f < FOUT; ++f) w[fi][f] = W[fi * FOUT + f];

    {
        const int m4 = (int)(threadIdx.x << 2);
        const float* xbp = xin + (size_t)b * FIN * N + m4;
        float4 xv[FIN];
#pragma unroll
        for (int fi = 0; fi < FIN; ++fi)
            xv[fi] = *(const float4*)(xbp + fi * N);
#pragma unroll
        for (int f = 0; f < FOUT; ++f) {
            float4 a = make_float4(0.f, 0.f, 0.f, 0.f);
#pragma unroll
            for (int fi = 0; fi < FIN; ++fi) {
                a.x += xv[fi].x * w[fi][f];
                a.y += xv[fi].y * w[fi][f];
                a.z += xv[fi].z * w[fi][f];
                a.w += xv[fi].w * w[fi][f];
            }
            *(float4*)&yds[f * N + m4] = a;
        }
    }
    __syncthreads();
    adj_rows_tanh_write<FOUT>(adj + (size_t)b * N * N, yds,
                              xout + (size_t)b * FOUT * N, n0);
}

// Layer 1: reads X [B][N][8] directly  [HW-verified]
__device__ __forceinline__ void do_layer1(const float* __restrict__ X,
                                          const float* __restrict__ adj,
                                          const float* __restrict__ W,
                                          float* __restrict__ xout,
                                          float* __restrict__ yds, int b, int n0) {
    float w[8][7];
#pragma unroll
    for (int fi = 0; fi < 8; ++fi)
#pragma unroll
        for (int f = 0; f < 7; ++f) w[fi][f] = W[fi * 7 + f];

    {
        const int m4 = (int)(threadIdx.x << 2);
        const float* xp = X + (size_t)b * 8192 + (size_t)m4 * 8;
        float4 lo[4], hi[4];
#pragma unroll
        for (int j = 0; j < 4; ++j) {
            lo[j] = *(const float4*)(xp + j * 8);
            hi[j] = *(const float4*)(xp + j * 8 + 4);
        }
#pragma unroll
        for (int f = 0; f < 7; ++f) {
            float4 a;
            a.x = lo[0].x * w[0][f] + lo[0].y * w[1][f] + lo[0].z * w[2][f] + lo[0].w * w[3][f]
                + hi[0].x * w[4][f] + hi[0].y * w[5][f] + hi[0].z * w[6][f] + hi[0].w * w[7][f];
            a.y = lo[1].x * w[0][f] + lo[1].y * w[1][f] + lo[1].z * w[2][f] + lo[1].w * w[3][f]
                + hi[1].x * w[4][f] + hi[1].y * w[5][f] + hi[1].z * w[6][f] + hi[1].w * w[7][f];
            a.z = lo[2].x * w[0][f] + lo[2].y * w[1][f] + lo[2].z * w[2][f] + lo[2].w * w[3][f]
                + hi[2].x * w[4][f] + hi[2].y * w[5][f] + hi[2].z * w[6][f] + hi[2].w * w[7][f];
            a.w = lo[3].x * w[0][f] + lo[3].y * w[1][f] + lo[3].z * w[2][f] + lo[3].w * w[3][f]
                + hi[3].x * w[4][f] + hi[3].y * w[5][f] + hi[3].z * w[6][f] + hi[3].w * w[7][f];
            *(float4*)&yds[f * N + m4] = a;
        }
    }
    __syncthreads();
    adj_rows_tanh_write<7>(adj + (size_t)b * N * N, yds,
                           xout + (size_t)b * 7 * N, n0);
}

// mu/lv heads + reparameterization. [HW-verified r2/r4/r5/r7]
__device__ __forceinline__ void do_muvl(const float* __restrict__ xin,
                                        const float* __restrict__ adj,
                                        const float* __restrict__ eps,
                                        const float* __restrict__ Wmu,
                                        const float* __restrict__ Wlv,
                                        float* __restrict__ out,
                                        float* __restrict__ yds, int b, int n0) {
    const float wm0 = Wmu[0], wm1 = Wmu[1];
    const float wl0 = Wlv[0], wl1 = Wlv[1];
    {
        const int m4 = (int)(threadIdx.x << 2);
        const float* xp = xin + (size_t)b * 2 * N;
        float4 x0 = *(const float4*)(xp + m4);
        float4 x1 = *(const float4*)(xp + N + m4);
        float4 ym, yl;
        ym.x = x0.x * wm0 + x1.x * wm1;  ym.y = x0.y * wm0 + x1.y * wm1;
        ym.z = x0.z * wm0 + x1.z * wm1;  ym.w = x0.w * wm0 + x1.w * wm1;
        yl.x = x0.x * wl0 + x1.x * wl1;  yl.y = x0.y * wl0 + x1.y * wl1;
        yl.z = x0.z * wl0 + x1.z * wl1;  yl.w = x0.w * wl0 + x1.w * wl1;
        *(float4*)&yds[m4]     = ym;
        *(float4*)&yds[N + m4] = yl;
    }
    __syncthreads();

    const int wave = (int)(threadIdx.x >> 6);
    const int lane = (int)(threadIdx.x & 63);
    const float* adjb = adj + (size_t)b * N * N;
    for (int half = 0; half < 4; ++half) {
        const int nb = n0 + half * 16 + (wave << 2);
        float v[32];
#pragma unroll
        for (int i = 0; i < 32; ++i) v[i] = 0.f;
#pragma unroll
        for (int k = 0; k < 4; ++k) {
            const int m = (k << 8) + (lane << 2);
            const float4 ym4 = *(const float4*)&yds[m];
            const float4 yl4 = *(const float4*)&yds[N + m];
#pragma unroll
            for (int r = 0; r < 4; ++r) {
                const float4 a4 = *(const float4*)(adjb + (size_t)(nb + r) * N + m);
                v[r * 8 + 0] += a4.x * ym4.x + a4.y * ym4.y + a4.z * ym4.z + a4.w * ym4.w;
                v[r * 8 + 1] += a4.x * yl4.x + a4.y * yl4.y + a4.z * yl4.z + a4.w * yl4.w;
            }
        }
        const float tot = reduce32(v);
        const float partner = __shfl_xor(tot, 16, 64);   // scalar s^1 (mu<->lv)
        const int s = rev5(lane & 31);
        if (lane < 32 && (s & 7) == 0) {
            const int r = s >> 3;
            const int n = nb + r;
            const float zm = tot, zlv = partner;
            const float e = eps[b * N + n];
            const float z = zm + e * expf(0.5f * zlv);
            out[b * N + n]         = z;
            out[32768 + b * N + n] = zm;
            out[65536 + b * N + n] = zlv;
        }
    }
}

// ---------------------------------------------------------------------------
// Fused stages 1-7. REGULAR launch, 512 blocks (16/batch, 64 rows/block).
// ---------------------------------------------------------------------------
__global__ __launch_bounds__(256, 4) void gvae_layers(
    const float* __restrict__ X, const float* __restrict__ adj,
    const float* __restrict__ eps,
    const float* __restrict__ W0, const float* __restrict__ W1,
    const float* __restrict__ W2, const float* __restrict__ W3,
    const float* __restrict__ W4, const float* __restrict__ W5,
    const float* __restrict__ Wmu, const float* __restrict__ Wlv,
    float* __restrict__ out, float* __restrict__ bufA,
    float* __restrict__ bufB, unsigned* __restrict__ ctrs) {
    __shared__ float yds[7 * N];          // 28 KB
    const int blk = (int)blockIdx.x;
    const int b   = blk >> 4;             // 16 blocks per batch
    const int n0  = (blk & 15) << 6;      // 64 rows per block
    unsigned* ctr = ctrs + b * CTRS;

    do_layer1(X, adj, W0, bufA, yds, b, n0);            batch_barrier(ctr, BPB * 1);
    do_layer<7, 6>(bufA, adj, W1, bufB, yds, b, n0);    batch_barrier(ctr, BPB * 2);
    do_layer<6, 5>(bufB, adj, W2, bufA, yds, b, n0);    batch_barrier(ctr, BPB * 3);
    do_layer<5, 4>(bufA, adj, W3, bufB, yds, b, n0);    batch_barrier(ctr, BPB * 4);
    do_layer<4, 3>(bufB, adj, W4, bufA, yds, b, n0);    batch_barrier(ctr, BPB * 5);
    do_layer<3, 2>(bufA, adj, W5, bufB, yds, b, n0);    batch_barrier(ctr, BPB * 6);
    do_muvl(bufB, adj, eps, Wmu, Wlv, out, yds, b, n0);
}

// ---------------------------------------------------------------------------
// adj_pred[b][n][m] = z[b][n] * z[b][m]  [HW-verified regular dispatch]
// ---------------------------------------------------------------------------
__global__ __launch_bounds__(256) void adjpred_k(const float* __restrict__ z,
                                                 float* __restrict__ out) {
    const int b = blockIdx.x >> 10;
    const int n = blockIdx.x & 1023;
    const float zn = z[b * N + n];
    const int m4 = threadIdx.x << 2;
    const float4 zm4 = *(const float4*)(z + b * N + m4);
    float4 o;
    o.x = zn * zm4.x; o.y = zn * zm4.y; o.z = zn * zm4.z; o.w = zn * zm4.w;
    *(float4*)(out + ((size_t)b << 20) + ((size_t)n << 10) + m4) = o;
}

// ---------------------------------------------------------------------------
extern "C" void kernel_launch(void* const* d_in, const int* in_sizes, int n_in,
                              void* d_out, int out_size, void* d_ws, size_t ws_size,
                              hipStream_t stream) {
    const float* X   = (const float*)d_in[0];
    const float* adj = (const float*)d_in[1];
    const float* eps = (const float*)d_in[2];
    const float* W0  = (const float*)d_in[3];
    const float* W1  = (const float*)d_in[4];
    const float* W2  = (const float*)d_in[5];
    const float* W3  = (const float*)d_in[6];
    const float* W4  = (const float*)d_in[7];
    const float* W5  = (const float*)d_in[8];
    const float* Wmu = (const float*)d_in[9];
    const float* Wlv = (const float*)d_in[10];

    float* out  = (float*)d_out;
    float* bufA = (float*)d_ws;                       // <= 7*32*1024 floats
    float* bufB = bufA + (size_t)7 * B * N;           // <= 7*32*1024 floats
    unsigned* ctrs = (unsigned*)(bufB + (size_t)7 * B * N);  // 32*CTRS u32

    (void)hipMemsetAsync(ctrs, 0, B * CTRS * sizeof(unsigned), stream);

    gvae_layers<<<dim3(B * BPB), dim3(256), 0, stream>>>(
        X, adj, eps, W0, W1, W2, W3, W4, W5, Wmu, Wlv, out, bufA, bufB, ctrs);

    adjpred_k<<<B * N, 256, 0, stream>>>(out, out + 98304);
}

// Round 9
// 227.928 us; speedup vs baseline: 4.6433x; 3.7404x over previous
//
#include <hip/hip_runtime.h>
#include <cstddef>

static constexpr int B = 32;
static constexpr int N = 1024;

// ---------------------------------------------------------------------------
// 5-bit bit-reversal (involution): lane -> scalar index after log-reduce
// ---------------------------------------------------------------------------
__device__ __forceinline__ int rev5(int l) {
    return ((l & 1) << 4) | ((l & 2) << 2) | (l & 4) | ((l & 8) >> 2) | ((l & 16) >> 4);
}

// ---------------------------------------------------------------------------
// Logarithmic multi-scalar reduce: v[32] per-lane partials -> lane l (and
// l+32) holds full 64-lane sum of scalar rev5(l&31). 63 shuffles.
// [HW-verified r2/r4/r5/r7/r8]
// ---------------------------------------------------------------------------
__device__ __forceinline__ float reduce32(float (&v)[32]) {
    const int lane = (int)(threadIdx.x & 63);
    float a[16], b[8], c[4], d[2];
#pragma unroll
    for (int i = 0; i < 16; ++i) {
        float lo = v[i]      + __shfl_xor(v[i],      1, 64);
        float hi = v[i + 16] + __shfl_xor(v[i + 16], 1, 64);
        a[i] = (lane & 1) ? hi : lo;
    }
#pragma unroll
    for (int i = 0; i < 8; ++i) {
        float lo = a[i]     + __shfl_xor(a[i],     2, 64);
        float hi = a[i + 8] + __shfl_xor(a[i + 8], 2, 64);
        b[i] = (lane & 2) ? hi : lo;
    }
#pragma unroll
    for (int i = 0; i < 4; ++i) {
        float lo = b[i]     + __shfl_xor(b[i],     4, 64);
        float hi = b[i + 4] + __shfl_xor(b[i + 4], 4, 64);
        c[i] = (lane & 4) ? hi : lo;
    }
#pragma unroll
    for (int i = 0; i < 2; ++i) {
        float lo = c[i]     + __shfl_xor(c[i],     8, 64);
        float hi = c[i + 2] + __shfl_xor(c[i + 2], 8, 64);
        d[i] = (lane & 8) ? hi : lo;
    }
    {
        float lo = d[0] + __shfl_xor(d[0], 16, 64);
        float hi = d[1] + __shfl_xor(d[1], 16, 64);
        float e  = (lane & 16) ? hi : lo;
        e += __shfl_xor(e, 32, 64);
        return e;
    }
}

// ---------------------------------------------------------------------------
// m-loop for 16 rows/block (4 rows/wave), dot vs yds[FOUT][N], log-reduce,
// tanh, write xout[b][FOUT][N]. [HW-verified math]
// ---------------------------------------------------------------------------
template <int FOUT>
__device__ __forceinline__ void adj_rows_tanh_write(const float* __restrict__ adjb,
                                                    const float* __restrict__ yds,
                                                    float* __restrict__ xoutb, int n0) {
    const int wave = (int)(threadIdx.x >> 6);
    const int lane = (int)(threadIdx.x & 63);
    const int nb   = n0 + (wave << 2);
    float v[32];
#pragma unroll
    for (int i = 0; i < 32; ++i) v[i] = 0.f;
#pragma unroll
    for (int k = 0; k < 4; ++k) {
        const int m = (k << 8) + (lane << 2);
        float4 a4[4];
#pragma unroll
        for (int r = 0; r < 4; ++r)
            a4[r] = *(const float4*)(adjb + (size_t)(nb + r) * N + m);
#pragma unroll
        for (int f = 0; f < FOUT; ++f) {
            const float4 yv = *(const float4*)&yds[f * N + m];
#pragma unroll
            for (int r = 0; r < 4; ++r)
                v[r * 8 + f] += a4[r].x * yv.x + a4[r].y * yv.y +
                                a4[r].z * yv.z + a4[r].w * yv.w;
        }
    }
    const float tot = reduce32(v);
    const int s = rev5(lane & 31);
    const int r = s >> 3, f = s & 7;
    if (lane < 32 && f < FOUT)
        xoutb[(size_t)f * N + nb + r] = tanhf(tot);
}

// ---------------------------------------------------------------------------
// Generic layer kernel: xout = tanh(adj[b] @ (xin[b] @ W)), xin [B][FIN][N].
// grid 2048 = B*64 blocks, 16 rows/block. [HW-verified math r1/r7/r8]
// ---------------------------------------------------------------------------
template <int FIN, int FOUT>
__global__ __launch_bounds__(256, 4) void layer_k(const float* __restrict__ xin,
                                                  const float* __restrict__ adj,
                                                  const float* __restrict__ W,
                                                  float* __restrict__ xout) {
    __shared__ float yds[FOUT * N];
    const int b  = (int)(blockIdx.x >> 6);
    const int n0 = (int)(blockIdx.x & 63) << 4;

    float w[FIN][FOUT];
#pragma unroll
    for (int fi = 0; fi < FIN; ++fi)
#pragma unroll
        for (int f = 0; f < FOUT; ++f) w[fi][f] = W[fi * FOUT + f];

    {
        const int m4 = (int)(threadIdx.x << 2);
        const float* xbp = xin + (size_t)b * FIN * N + m4;
        float4 xv[FIN];
#pragma unroll
        for (int fi = 0; fi < FIN; ++fi)
            xv[fi] = *(const float4*)(xbp + fi * N);
#pragma unroll
        for (int f = 0; f < FOUT; ++f) {
            float4 a = make_float4(0.f, 0.f, 0.f, 0.f);
#pragma unroll
            for (int fi = 0; fi < FIN; ++fi) {
                a.x += xv[fi].x * w[fi][f];
                a.y += xv[fi].y * w[fi][f];
                a.z += xv[fi].z * w[fi][f];
                a.w += xv[fi].w * w[fi][f];
            }
            *(float4*)&yds[f * N + m4] = a;
        }
    }
    __syncthreads();
    adj_rows_tanh_write<FOUT>(adj + (size_t)b * N * N, yds,
                              xout + (size_t)b * FOUT * N, n0);
}

// ---------------------------------------------------------------------------
// Layer 1: reads X [B][N][8] directly (no transpose dispatch).
// [HW-verified r7/r8]
// ---------------------------------------------------------------------------
__global__ __launch_bounds__(256, 4) void layer1_k(const float* __restrict__ X,
                                                   const float* __restrict__ adj,
                                                   const float* __restrict__ W,
                                                   float* __restrict__ xout) {
    __shared__ float yds[7 * N];
    const int b  = (int)(blockIdx.x >> 6);
    const int n0 = (int)(blockIdx.x & 63) << 4;

    float w[8][7];
#pragma unroll
    for (int fi = 0; fi < 8; ++fi)
#pragma unroll
        for (int f = 0; f < 7; ++f) w[fi][f] = W[fi * 7 + f];

    {
        const int m4 = (int)(threadIdx.x << 2);
        const float* xp = X + (size_t)b * 8192 + (size_t)m4 * 8;
        float4 lo[4], hi[4];
#pragma unroll
        for (int j = 0; j < 4; ++j) {
            lo[j] = *(const float4*)(xp + j * 8);
            hi[j] = *(const float4*)(xp + j * 8 + 4);
        }
#pragma unroll
        for (int f = 0; f < 7; ++f) {
            float4 a;
            a.x = lo[0].x * w[0][f] + lo[0].y * w[1][f] + lo[0].z * w[2][f] + lo[0].w * w[3][f]
                + hi[0].x * w[4][f] + hi[0].y * w[5][f] + hi[0].z * w[6][f] + hi[0].w * w[7][f];
            a.y = lo[1].x * w[0][f] + lo[1].y * w[1][f] + lo[1].z * w[2][f] + lo[1].w * w[3][f]
                + hi[1].x * w[4][f] + hi[1].y * w[5][f] + hi[1].z * w[6][f] + hi[1].w * w[7][f];
            a.z = lo[2].x * w[0][f] + lo[2].y * w[1][f] + lo[2].z * w[2][f] + lo[2].w * w[3][f]
                + hi[2].x * w[4][f] + hi[2].y * w[5][f] + hi[2].z * w[6][f] + hi[2].w * w[7][f];
            a.w = lo[3].x * w[0][f] + lo[3].y * w[1][f] + lo[3].z * w[2][f] + lo[3].w * w[3][f]
                + hi[3].x * w[4][f] + hi[3].y * w[5][f] + hi[3].z * w[6][f] + hi[3].w * w[7][f];
            *(float4*)&yds[f * N + m4] = a;
        }
    }
    __syncthreads();
    adj_rows_tanh_write<7>(adj + (size_t)b * N * N, yds,
                           xout + (size_t)b * 7 * N, n0);
}

// ---------------------------------------------------------------------------
// mu/lv heads + reparameterization; out: z @0, z_mean @32768, z_log_var @65536.
// grid 2048, 16 rows/block. [HW-verified math r2..r8]
// ---------------------------------------------------------------------------
__global__ __launch_bounds__(256, 4) void muvl_k(const float* __restrict__ xin,
                                                 const float* __restrict__ adj,
                                                 const float* __restrict__ eps,
                                                 const float* __restrict__ Wmu,
                                                 const float* __restrict__ Wlv,
                                                 float* __restrict__ out) {
    __shared__ float yds[2 * N];
    const int b  = (int)(blockIdx.x >> 6);
    const int n0 = (int)(blockIdx.x & 63) << 4;

    const float wm0 = Wmu[0], wm1 = Wmu[1];
    const float wl0 = Wlv[0], wl1 = Wlv[1];
    {
        const int m4 = (int)(threadIdx.x << 2);
        const float* xp = xin + (size_t)b * 2 * N;
        float4 x0 = *(const float4*)(xp + m4);
        float4 x1 = *(const float4*)(xp + N + m4);
        float4 ym, yl;
        ym.x = x0.x * wm0 + x1.x * wm1;  ym.y = x0.y * wm0 + x1.y * wm1;
        ym.z = x0.z * wm0 + x1.z * wm1;  ym.w = x0.w * wm0 + x1.w * wm1;
        yl.x = x0.x * wl0 + x1.x * wl1;  yl.y = x0.y * wl0 + x1.y * wl1;
        yl.z = x0.z * wl0 + x1.z * wl1;  yl.w = x0.w * wl0 + x1.w * wl1;
        *(float4*)&yds[m4]     = ym;
        *(float4*)&yds[N + m4] = yl;
    }
    __syncthreads();

    const int wave = (int)(threadIdx.x >> 6);
    const int lane = (int)(threadIdx.x & 63);
    const float* adjb = adj + (size_t)b * N * N;
    const int nb = n0 + (wave << 2);
    float v[32];
#pragma unroll
    for (int i = 0; i < 32; ++i) v[i] = 0.f;
#pragma unroll
    for (int k = 0; k < 4; ++k) {
        const int m = (k << 8) + (lane << 2);
        const float4 ym4 = *(const float4*)&yds[m];
        const float4 yl4 = *(const float4*)&yds[N + m];
#pragma unroll
        for (int r = 0; r < 4; ++r) {
            const float4 a4 = *(const float4*)(adjb + (size_t)(nb + r) * N + m);
            v[r * 8 + 0] += a4.x * ym4.x + a4.y * ym4.y + a4.z * ym4.z + a4.w * ym4.w;
            v[r * 8 + 1] += a4.x * yl4.x + a4.y * yl4.y + a4.z * yl4.z + a4.w * yl4.w;
        }
    }
    const float tot = reduce32(v);
    const float partner = __shfl_xor(tot, 16, 64);   // scalar s^1 (mu<->lv)
    const int s = rev5(lane & 31);
    if (lane < 32 && (s & 7) == 0) {
        const int r = s >> 3;
        const int n = nb + r;
        const float zm = tot, zlv = partner;
        const float e = eps[b * N + n];
        const float z = zm + e * expf(0.5f * zlv);
        out[b * N + n]         = z;
        out[32768 + b * N + n] = zm;
        out[65536 + b * N + n] = zlv;
    }
}

// ---------------------------------------------------------------------------
// adj_pred[b][n][m] = z[b][n] * z[b][m]  — round-1 kernel VERBATIM
// (HW-verified reading z from d_out across a regular dispatch boundary).
// ---------------------------------------------------------------------------
__global__ __launch_bounds__(256) void adjpred_k(const float* __restrict__ z,
                                                 float* __restrict__ out) {
    const int b = blockIdx.x >> 10;
    const int n = blockIdx.x & 1023;
    const float zn = z[b * N + n];
    const int m4 = threadIdx.x << 2;
    const float4 zm4 = *(const float4*)(z + b * N + m4);
    float4 o;
    o.x = zn * zm4.x; o.y = zn * zm4.y; o.z = zn * zm4.z; o.w = zn * zm4.w;
    *(float4*)(out + ((size_t)b << 20) + ((size_t)n << 10) + m4) = o;
}

// ---------------------------------------------------------------------------
extern "C" void kernel_launch(void* const* d_in, const int* in_sizes, int n_in,
                              void* d_out, int out_size, void* d_ws, size_t ws_size,
                              hipStream_t stream) {
    const float* X   = (const float*)d_in[0];
    const float* adj = (const float*)d_in[1];
    const float* eps = (const float*)d_in[2];
    const float* W0  = (const float*)d_in[3];
    const float* W1  = (const float*)d_in[4];
    const float* W2  = (const float*)d_in[5];
    const float* W3  = (const float*)d_in[6];
    const float* W4  = (const float*)d_in[7];
    const float* W5  = (const float*)d_in[8];
    const float* Wmu = (const float*)d_in[9];
    const float* Wlv = (const float*)d_in[10];

    float* out  = (float*)d_out;
    float* bufA = (float*)d_ws;                  // [B][7][N] ping
    float* bufB = bufA + (size_t)7 * B * N;      // [B][7][N] pong

    layer1_k      <<<2048, 256, 0, stream>>>(X,    adj, W0, bufA);
    layer_k<7, 6> <<<2048, 256, 0, stream>>>(bufA, adj, W1, bufB);
    layer_k<6, 5> <<<2048, 256, 0, stream>>>(bufB, adj, W2, bufA);
    layer_k<5, 4> <<<2048, 256, 0, stream>>>(bufA, adj, W3, bufB);
    layer_k<4, 3> <<<2048, 256, 0, stream>>>(bufB, adj, W4, bufA);
    layer_k<3, 2> <<<2048, 256, 0, stream>>>(bufA, adj, W5, bufB);

    muvl_k<<<2048, 256, 0, stream>>>(bufB, adj, eps, Wmu, Wlv, out);

    adjpred_k<<<B * N, 256, 0, stream>>>(out, out + 98304);
}

// Round 10
// 185.057 us; speedup vs baseline: 5.7189x; 1.2317x over previous
//
#include <hip/hip_runtime.h>
#include <cstddef>

static constexpr int B = 32;
static constexpr int N = 1024;

// ---------------------------------------------------------------------------
// bf16 helpers (manual, RNE; adj is uniform[0,1) so no NaN/Inf concerns)
// ---------------------------------------------------------------------------
__device__ __forceinline__ unsigned short f2bf(float x) {
    unsigned u = __float_as_uint(x);
    return (unsigned short)((u + 0x7FFFu + ((u >> 16) & 1u)) >> 16);
}
__device__ __forceinline__ float bf2f(unsigned short b) {
    return __uint_as_float((unsigned)b << 16);
}

// ---------------------------------------------------------------------------
// 5-bit bit-reversal (involution): lane -> scalar index after log-reduce
// ---------------------------------------------------------------------------
__device__ __forceinline__ int rev5(int l) {
    return ((l & 1) << 4) | ((l & 2) << 2) | (l & 4) | ((l & 8) >> 2) | ((l & 16) >> 4);
}

// ---------------------------------------------------------------------------
// Logarithmic multi-scalar reduce: v[32] per-lane partials -> lane l (and
// l+32) holds full 64-lane sum of scalar rev5(l&31). [HW-verified r2..r9]
// ---------------------------------------------------------------------------
__device__ __forceinline__ float reduce32(float (&v)[32]) {
    const int lane = (int)(threadIdx.x & 63);
    float a[16], b[8], c[4], d[2];
#pragma unroll
    for (int i = 0; i < 16; ++i) {
        float lo = v[i]      + __shfl_xor(v[i],      1, 64);
        float hi = v[i + 16] + __shfl_xor(v[i + 16], 1, 64);
        a[i] = (lane & 1) ? hi : lo;
    }
#pragma unroll
    for (int i = 0; i < 8; ++i) {
        float lo = a[i]     + __shfl_xor(a[i],     2, 64);
        float hi = a[i + 8] + __shfl_xor(a[i + 8], 2, 64);
        b[i] = (lane & 2) ? hi : lo;
    }
#pragma unroll
    for (int i = 0; i < 4; ++i) {
        float lo = b[i]     + __shfl_xor(b[i],     4, 64);
        float hi = b[i + 4] + __shfl_xor(b[i + 4], 4, 64);
        c[i] = (lane & 4) ? hi : lo;
    }
#pragma unroll
    for (int i = 0; i < 2; ++i) {
        float lo = c[i]     + __shfl_xor(c[i],     8, 64);
        float hi = c[i + 2] + __shfl_xor(c[i + 2], 8, 64);
        d[i] = (lane & 8) ? hi : lo;
    }
    {
        float lo = d[0] + __shfl_xor(d[0], 16, 64);
        float hi = d[1] + __shfl_xor(d[1], 16, 64);
        float e  = (lane & 16) ? hi : lo;
        e += __shfl_xor(e, 32, 64);
        return e;
    }
}

// ---------------------------------------------------------------------------
// f32-adj m-loop for 16 rows/block (4 rows/wave). [HW-verified]
// ---------------------------------------------------------------------------
template <int FOUT>
__device__ __forceinline__ void adj_rows_tanh_write(const float* __restrict__ adjb,
                                                    const float* __restrict__ yds,
                                                    float* __restrict__ xoutb, int n0) {
    const int wave = (int)(threadIdx.x >> 6);
    const int lane = (int)(threadIdx.x & 63);
    const int nb   = n0 + (wave << 2);
    float v[32];
#pragma unroll
    for (int i = 0; i < 32; ++i) v[i] = 0.f;
#pragma unroll
    for (int k = 0; k < 4; ++k) {
        const int m = (k << 8) + (lane << 2);
        float4 a4[4];
#pragma unroll
        for (int r = 0; r < 4; ++r)
            a4[r] = *(const float4*)(adjb + (size_t)(nb + r) * N + m);
#pragma unroll
        for (int f = 0; f < FOUT; ++f) {
            const float4 yv = *(const float4*)&yds[f * N + m];
#pragma unroll
            for (int r = 0; r < 4; ++r)
                v[r * 8 + f] += a4[r].x * yv.x + a4[r].y * yv.y +
                                a4[r].z * yv.z + a4[r].w * yv.w;
        }
    }
    const float tot = reduce32(v);
    const int s = rev5(lane & 31);
    const int r = s >> 3, f = s & 7;
    if (lane < 32 && f < FOUT)
        xoutb[(size_t)f * N + nb + r] = tanhf(tot);
}

// ---------------------------------------------------------------------------
// y-phase shared by all generic layers: yds = xin[b] @ W
// ---------------------------------------------------------------------------
template <int FIN, int FOUT>
__device__ __forceinline__ void y_phase(const float* __restrict__ xin,
                                        const float* __restrict__ W,
                                        float* __restrict__ yds, int b) {
    float w[FIN][FOUT];
#pragma unroll
    for (int fi = 0; fi < FIN; ++fi)
#pragma unroll
        for (int f = 0; f < FOUT; ++f) w[fi][f] = W[fi * FOUT + f];
    const int m4 = (int)(threadIdx.x << 2);
    const float* xbp = xin + (size_t)b * FIN * N + m4;
    float4 xv[FIN];
#pragma unroll
    for (int fi = 0; fi < FIN; ++fi)
        xv[fi] = *(const float4*)(xbp + fi * N);
#pragma unroll
    for (int f = 0; f < FOUT; ++f) {
        float4 a = make_float4(0.f, 0.f, 0.f, 0.f);
#pragma unroll
        for (int fi = 0; fi < FIN; ++fi) {
            a.x += xv[fi].x * w[fi][f];
            a.y += xv[fi].y * w[fi][f];
            a.z += xv[fi].z * w[fi][f];
            a.w += xv[fi].w * w[fi][f];
        }
        *(float4*)&yds[f * N + m4] = a;
    }
}

// ---------------------------------------------------------------------------
// Generic f32-adj layer kernel. grid 2048, 16 rows/block. [HW-verified r9]
// ---------------------------------------------------------------------------
template <int FIN, int FOUT>
__global__ __launch_bounds__(256, 4) void layer_k(const float* __restrict__ xin,
                                                  const float* __restrict__ adj,
                                                  const float* __restrict__ W,
                                                  float* __restrict__ xout) {
    __shared__ float yds[FOUT * N];
    const int b  = (int)(blockIdx.x >> 6);
    const int n0 = (int)(blockIdx.x & 63) << 4;
    y_phase<FIN, FOUT>(xin, W, yds, b);
    __syncthreads();
    adj_rows_tanh_write<FOUT>(adj + (size_t)b * N * N, yds,
                              xout + (size_t)b * FOUT * N, n0);
}

// ---------------------------------------------------------------------------
// Generic bf16-adj layer kernel: reads adj from the bf16 copy in ws.
// Same tiling; ushort4 (8B/lane) loads + shift-convert.
// ---------------------------------------------------------------------------
template <int FIN, int FOUT>
__global__ __launch_bounds__(256, 4) void layer_bf_k(const float* __restrict__ xin,
                                                     const unsigned short* __restrict__ adjbf,
                                                     const float* __restrict__ W,
                                                     float* __restrict__ xout) {
    __shared__ float yds[FOUT * N];
    const int b  = (int)(blockIdx.x >> 6);
    const int n0 = (int)(blockIdx.x & 63) << 4;
    y_phase<FIN, FOUT>(xin, W, yds, b);
    __syncthreads();

    const int wave = (int)(threadIdx.x >> 6);
    const int lane = (int)(threadIdx.x & 63);
    const int nb   = n0 + (wave << 2);
    const unsigned short* ab = adjbf + ((size_t)b << 20);
    float* xoutb = xout + (size_t)b * FOUT * N;

    float v[32];
#pragma unroll
    for (int i = 0; i < 32; ++i) v[i] = 0.f;
#pragma unroll
    for (int k = 0; k < 4; ++k) {
        const int m = (k << 8) + (lane << 2);
        float4 a4[4];
#pragma unroll
        for (int r = 0; r < 4; ++r) {
            const ushort4 raw = *(const ushort4*)(ab + (((size_t)(nb + r)) << 10) + m);
            a4[r].x = bf2f(raw.x); a4[r].y = bf2f(raw.y);
            a4[r].z = bf2f(raw.z); a4[r].w = bf2f(raw.w);
        }
#pragma unroll
        for (int f = 0; f < FOUT; ++f) {
            const float4 yv = *(const float4*)&yds[f * N + m];
#pragma unroll
            for (int r = 0; r < 4; ++r)
                v[r * 8 + f] += a4[r].x * yv.x + a4[r].y * yv.y +
                                a4[r].z * yv.z + a4[r].w * yv.w;
        }
    }
    const float tot = reduce32(v);
    const int s = rev5(lane & 31);
    const int r = s >> 3, f = s & 7;
    if (lane < 32 && f < FOUT)
        xoutb[(size_t)f * N + nb + r] = tanhf(tot);
}

// ---------------------------------------------------------------------------
// Layer 1: reads X [B][N][8] directly; optionally emits bf16 copy of adj
// (each block covers rows n0..n0+15 x all m exactly once).
// ---------------------------------------------------------------------------
template <bool STORE_BF>
__global__ __launch_bounds__(256, 4) void layer1_k(const float* __restrict__ X,
                                                   const float* __restrict__ adj,
                                                   const float* __restrict__ W,
                                                   float* __restrict__ xout,
                                                   unsigned short* __restrict__ adjbf) {
    __shared__ float yds[7 * N];
    const int b  = (int)(blockIdx.x >> 6);
    const int n0 = (int)(blockIdx.x & 63) << 4;

    float w[8][7];
#pragma unroll
    for (int fi = 0; fi < 8; ++fi)
#pragma unroll
        for (int f = 0; f < 7; ++f) w[fi][f] = W[fi * 7 + f];

    {
        const int m4 = (int)(threadIdx.x << 2);
        const float* xp = X + (size_t)b * 8192 + (size_t)m4 * 8;
        float4 lo[4], hi[4];
#pragma unroll
        for (int j = 0; j < 4; ++j) {
            lo[j] = *(const float4*)(xp + j * 8);
            hi[j] = *(const float4*)(xp + j * 8 + 4);
        }
#pragma unroll
        for (int f = 0; f < 7; ++f) {
            float4 a;
            a.x = lo[0].x * w[0][f] + lo[0].y * w[1][f] + lo[0].z * w[2][f] + lo[0].w * w[3][f]
                + hi[0].x * w[4][f] + hi[0].y * w[5][f] + hi[0].z * w[6][f] + hi[0].w * w[7][f];
            a.y = lo[1].x * w[0][f] + lo[1].y * w[1][f] + lo[1].z * w[2][f] + lo[1].w * w[3][f]
                + hi[1].x * w[4][f] + hi[1].y * w[5][f] + hi[1].z * w[6][f] + hi[1].w * w[7][f];
            a.z = lo[2].x * w[0][f] + lo[2].y * w[1][f] + lo[2].z * w[2][f] + lo[2].w * w[3][f]
                + hi[2].x * w[4][f] + hi[2].y * w[5][f] + hi[2].z * w[6][f] + hi[2].w * w[7][f];
            a.w = lo[3].x * w[0][f] + lo[3].y * w[1][f] + lo[3].z * w[2][f] + lo[3].w * w[3][f]
                + hi[3].x * w[4][f] + hi[3].y * w[5][f] + hi[3].z * w[6][f] + hi[3].w * w[7][f];
            *(float4*)&yds[f * N + m4] = a;
        }
    }
    __syncthreads();

    {
        const int wave = (int)(threadIdx.x >> 6);
        const int lane = (int)(threadIdx.x & 63);
        const int nb   = n0 + (wave << 2);
        const float* adjb = adj + (size_t)b * N * N;
        unsigned short* ab = adjbf + ((size_t)b << 20);
        float* xoutb = xout + (size_t)b * 7 * N;

        float v[32];
#pragma unroll
        for (int i = 0; i < 32; ++i) v[i] = 0.f;
#pragma unroll
        for (int k = 0; k < 4; ++k) {
            const int m = (k << 8) + (lane << 2);
            float4 a4[4];
#pragma unroll
            for (int r = 0; r < 4; ++r)
                a4[r] = *(const float4*)(adjb + (size_t)(nb + r) * N + m);
            if (STORE_BF) {
#pragma unroll
                for (int r = 0; r < 4; ++r) {
                    ushort4 s4;
                    s4.x = f2bf(a4[r].x); s4.y = f2bf(a4[r].y);
                    s4.z = f2bf(a4[r].z); s4.w = f2bf(a4[r].w);
                    *(ushort4*)(ab + (((size_t)(nb + r)) << 10) + m) = s4;
                }
            }
#pragma unroll
            for (int f = 0; f < 7; ++f) {
                const float4 yv = *(const float4*)&yds[f * N + m];
#pragma unroll
                for (int r = 0; r < 4; ++r)
                    v[r * 8 + f] += a4[r].x * yv.x + a4[r].y * yv.y +
                                    a4[r].z * yv.z + a4[r].w * yv.w;
            }
        }
        const float tot = reduce32(v);
        const int s = rev5(lane & 31);
        const int r = s >> 3, f = s & 7;
        if (lane < 32 && f < 7)
            xoutb[(size_t)f * N + nb + r] = tanhf(tot);
    }
}

// ---------------------------------------------------------------------------
// mu/lv heads + reparameterization (f32 adj — precision-critical: feeds
// exp(0.5*zlv)). [HW-verified r9]
// ---------------------------------------------------------------------------
__global__ __launch_bounds__(256, 4) void muvl_k(const float* __restrict__ xin,
                                                 const float* __restrict__ adj,
                                                 const float* __restrict__ eps,
                                                 const float* __restrict__ Wmu,
                                                 const float* __restrict__ Wlv,
                                                 float* __restrict__ out) {
    __shared__ float yds[2 * N];
    const int b  = (int)(blockIdx.x >> 6);
    const int n0 = (int)(blockIdx.x & 63) << 4;

    const float wm0 = Wmu[0], wm1 = Wmu[1];
    const float wl0 = Wlv[0], wl1 = Wlv[1];
    {
        const int m4 = (int)(threadIdx.x << 2);
        const float* xp = xin + (size_t)b * 2 * N;
        float4 x0 = *(const float4*)(xp + m4);
        float4 x1 = *(const float4*)(xp + N + m4);
        float4 ym, yl;
        ym.x = x0.x * wm0 + x1.x * wm1;  ym.y = x0.y * wm0 + x1.y * wm1;
        ym.z = x0.z * wm0 + x1.z * wm1;  ym.w = x0.w * wm0 + x1.w * wm1;
        yl.x = x0.x * wl0 + x1.x * wl1;  yl.y = x0.y * wl0 + x1.y * wl1;
        yl.z = x0.z * wl0 + x1.z * wl1;  yl.w = x0.w * wl0 + x1.w * wl1;
        *(float4*)&yds[m4]     = ym;
        *(float4*)&yds[N + m4] = yl;
    }
    __syncthreads();

    const int wave = (int)(threadIdx.x >> 6);
    const int lane = (int)(threadIdx.x & 63);
    const float* adjb = adj + (size_t)b * N * N;
    const int nb = n0 + (wave << 2);
    float v[32];
#pragma unroll
    for (int i = 0; i < 32; ++i) v[i] = 0.f;
#pragma unroll
    for (int k = 0; k < 4; ++k) {
        const int m = (k << 8) + (lane << 2);
        const float4 ym4 = *(const float4*)&yds[m];
        const float4 yl4 = *(const float4*)&yds[N + m];
#pragma unroll
        for (int r = 0; r < 4; ++r) {
            const float4 a4 = *(const float4*)(adjb + (size_t)(nb + r) * N + m);
            v[r * 8 + 0] += a4.x * ym4.x + a4.y * ym4.y + a4.z * ym4.z + a4.w * ym4.w;
            v[r * 8 + 1] += a4.x * yl4.x + a4.y * yl4.y + a4.z * yl4.z + a4.w * yl4.w;
        }
    }
    const float tot = reduce32(v);
    const float partner = __shfl_xor(tot, 16, 64);   // scalar s^1 (mu<->lv)
    const int s = rev5(lane & 31);
    if (lane < 32 && (s & 7) == 0) {
        const int r = s >> 3;
        const int n = nb + r;
        const float zm = tot, zlv = partner;
        const float e = eps[b * N + n];
        const float z = zm + e * expf(0.5f * zlv);
        out[b * N + n]         = z;
        out[32768 + b * N + n] = zm;
        out[65536 + b * N + n] = zlv;
    }
}

// ---------------------------------------------------------------------------
// adj_pred[b][n][m] = z[b][n] * z[b][m]  [HW-verified r1/r9]
// ---------------------------------------------------------------------------
__global__ __launch_bounds__(256) void adjpred_k(const float* __restrict__ z,
                                                 float* __restrict__ out) {
    const int b = blockIdx.x >> 10;
    const int n = blockIdx.x & 1023;
    const float zn = z[b * N + n];
    const int m4 = threadIdx.x << 2;
    const float4 zm4 = *(const float4*)(z + b * N + m4);
    float4 o;
    o.x = zn * zm4.x; o.y = zn * zm4.y; o.z = zn * zm4.z; o.w = zn * zm4.w;
    *(float4*)(out + ((size_t)b << 20) + ((size_t)n << 10) + m4) = o;
}

// ---------------------------------------------------------------------------
extern "C" void kernel_launch(void* const* d_in, const int* in_sizes, int n_in,
                              void* d_out, int out_size, void* d_ws, size_t ws_size,
                              hipStream_t stream) {
    const float* X   = (const float*)d_in[0];
    const float* adj = (const float*)d_in[1];
    const float* eps = (const float*)d_in[2];
    const float* W0  = (const float*)d_in[3];
    const float* W1  = (const float*)d_in[4];
    const float* W2  = (const float*)d_in[5];
    const float* W3  = (const float*)d_in[6];
    const float* W4  = (const float*)d_in[7];
    const float* W5  = (const float*)d_in[8];
    const float* Wmu = (const float*)d_in[9];
    const float* Wlv = (const float*)d_in[10];

    float* out  = (float*)d_out;
    float* bufA = (float*)d_ws;                  // [B][7][N] ping
    float* bufB = bufA + (size_t)7 * B * N;      // [B][7][N] pong
    unsigned short* adjbf = (unsigned short*)(bufB + (size_t)7 * B * N);

    const size_t need = (size_t)14 * B * N * sizeof(float)
                      + (size_t)B * N * N * sizeof(unsigned short);

    if (ws_size >= need) {
        // bf16-adj path: layer1 converts adj f32->bf16 while doing pass 1;
        // layers 2-5 read the 67MB bf16 copy; layer 6 + muvl stay f32.
        layer1_k<true>  <<<2048, 256, 0, stream>>>(X, adj, W0, bufA, adjbf);
        layer_bf_k<7, 6><<<2048, 256, 0, stream>>>(bufA, adjbf, W1, bufB);
        layer_bf_k<6, 5><<<2048, 256, 0, stream>>>(bufB, adjbf, W2, bufA);
        layer_bf_k<5, 4><<<2048, 256, 0, stream>>>(bufA, adjbf, W3, bufB);
        layer_bf_k<4, 3><<<2048, 256, 0, stream>>>(bufB, adjbf, W4, bufA);
        layer_k<3, 2>   <<<2048, 256, 0, stream>>>(bufA, adj, W5, bufB);
    } else {
        // Fallback: all-f32 (r9-verified path)
        layer1_k<false> <<<2048, 256, 0, stream>>>(X, adj, W0, bufA, adjbf);
        layer_k<7, 6>   <<<2048, 256, 0, stream>>>(bufA, adj, W1, bufB);
        layer_k<6, 5>   <<<2048, 256, 0, stream>>>(bufB, adj, W2, bufA);
        layer_k<5, 4>   <<<2048, 256, 0, stream>>>(bufA, adj, W3, bufB);
        layer_k<4, 3>   <<<2048, 256, 0, stream>>>(bufB, adj, W4, bufA);
        layer_k<3, 2>   <<<2048, 256, 0, stream>>>(bufA, adj, W5, bufB);
    }

    muvl_k<<<2048, 256, 0, stream>>>(bufB, adj, eps, Wmu, Wlv, out);

    adjpred_k<<<B * N, 256, 0, stream>>>(out, out + 98304);
}

// Round 11
// 155.487 us; speedup vs baseline: 6.8065x; 1.1902x over previous
//
#include <hip/hip_runtime.h>
#include <cstddef>

static constexpr int B = 32;
static constexpr int N = 1024;

// ---------------------------------------------------------------------------
// bf16 helpers (manual, RNE; adj is uniform[0,1) so no NaN/Inf concerns)
// ---------------------------------------------------------------------------
__device__ __forceinline__ unsigned short f2bf(float x) {
    unsigned u = __float_as_uint(x);
    return (unsigned short)((u + 0x7FFFu + ((u >> 16) & 1u)) >> 16);
}
__device__ __forceinline__ float bf2f(unsigned short b) {
    return __uint_as_float((unsigned)b << 16);
}

// ---------------------------------------------------------------------------
// 5-bit bit-reversal (involution): lane -> scalar index after log-reduce
// ---------------------------------------------------------------------------
__device__ __forceinline__ int rev5(int l) {
    return ((l & 1) << 4) | ((l & 2) << 2) | (l & 4) | ((l & 8) >> 2) | ((l & 16) >> 4);
}

// ---------------------------------------------------------------------------
// Logarithmic multi-scalar reduce: v[32] per-lane partials -> lane l (and
// l+32) holds full 64-lane sum of scalar rev5(l&31). [HW-verified r2..r10]
// ---------------------------------------------------------------------------
__device__ __forceinline__ float reduce32(float (&v)[32]) {
    const int lane = (int)(threadIdx.x & 63);
    float a[16], b[8], c[4], d[2];
#pragma unroll
    for (int i = 0; i < 16; ++i) {
        float lo = v[i]      + __shfl_xor(v[i],      1, 64);
        float hi = v[i + 16] + __shfl_xor(v[i + 16], 1, 64);
        a[i] = (lane & 1) ? hi : lo;
    }
#pragma unroll
    for (int i = 0; i < 8; ++i) {
        float lo = a[i]     + __shfl_xor(a[i],     2, 64);
        float hi = a[i + 8] + __shfl_xor(a[i + 8], 2, 64);
        b[i] = (lane & 2) ? hi : lo;
    }
#pragma unroll
    for (int i = 0; i < 4; ++i) {
        float lo = b[i]     + __shfl_xor(b[i],     4, 64);
        float hi = b[i + 4] + __shfl_xor(b[i + 4], 4, 64);
        c[i] = (lane & 4) ? hi : lo;
    }
#pragma unroll
    for (int i = 0; i < 2; ++i) {
        float lo = c[i]     + __shfl_xor(c[i],     8, 64);
        float hi = c[i + 2] + __shfl_xor(c[i + 2], 8, 64);
        d[i] = (lane & 8) ? hi : lo;
    }
    {
        float lo = d[0] + __shfl_xor(d[0], 16, 64);
        float hi = d[1] + __shfl_xor(d[1], 16, 64);
        float e  = (lane & 16) ? hi : lo;
        e += __shfl_xor(e, 32, 64);
        return e;
    }
}

// ---------------------------------------------------------------------------
// f32-adj m-loop for 16 rows/block (4 rows/wave). [HW-verified]
// ---------------------------------------------------------------------------
template <int FOUT>
__device__ __forceinline__ void adj_rows_tanh_write(const float* __restrict__ adjb,
                                                    const float* __restrict__ yds,
                                                    float* __restrict__ xoutb, int n0) {
    const int wave = (int)(threadIdx.x >> 6);
    const int lane = (int)(threadIdx.x & 63);
    const int nb   = n0 + (wave << 2);
    float v[32];
#pragma unroll
    for (int i = 0; i < 32; ++i) v[i] = 0.f;
#pragma unroll
    for (int k = 0; k < 4; ++k) {
        const int m = (k << 8) + (lane << 2);
        float4 a4[4];
#pragma unroll
        for (int r = 0; r < 4; ++r)
            a4[r] = *(const float4*)(adjb + (size_t)(nb + r) * N + m);
#pragma unroll
        for (int f = 0; f < FOUT; ++f) {
            const float4 yv = *(const float4*)&yds[f * N + m];
#pragma unroll
            for (int r = 0; r < 4; ++r)
                v[r * 8 + f] += a4[r].x * yv.x + a4[r].y * yv.y +
                                a4[r].z * yv.z + a4[r].w * yv.w;
        }
    }
    const float tot = reduce32(v);
    const int s = rev5(lane & 31);
    const int r = s >> 3, f = s & 7;
    if (lane < 32 && f < FOUT)
        xoutb[(size_t)f * N + nb + r] = tanhf(tot);
}

// ---------------------------------------------------------------------------
// y-phase shared by all generic layers: yds = xin[b] @ W
// ---------------------------------------------------------------------------
template <int FIN, int FOUT>
__device__ __forceinline__ void y_phase(const float* __restrict__ xin,
                                        const float* __restrict__ W,
                                        float* __restrict__ yds, int b) {
    float w[FIN][FOUT];
#pragma unroll
    for (int fi = 0; fi < FIN; ++fi)
#pragma unroll
        for (int f = 0; f < FOUT; ++f) w[fi][f] = W[fi * FOUT + f];
    const int m4 = (int)(threadIdx.x << 2);
    const float* xbp = xin + (size_t)b * FIN * N + m4;
    float4 xv[FIN];
#pragma unroll
    for (int fi = 0; fi < FIN; ++fi)
        xv[fi] = *(const float4*)(xbp + fi * N);
#pragma unroll
    for (int f = 0; f < FOUT; ++f) {
        float4 a = make_float4(0.f, 0.f, 0.f, 0.f);
#pragma unroll
        for (int fi = 0; fi < FIN; ++fi) {
            a.x += xv[fi].x * w[fi][f];
            a.y += xv[fi].y * w[fi][f];
            a.z += xv[fi].z * w[fi][f];
            a.w += xv[fi].w * w[fi][f];
        }
        *(float4*)&yds[f * N + m4] = a;
    }
}

// ---------------------------------------------------------------------------
// Generic f32-adj layer kernel. grid 2048, 16 rows/block. [HW-verified r9/r10]
// ---------------------------------------------------------------------------
template <int FIN, int FOUT>
__global__ __launch_bounds__(256, 4) void layer_k(const float* __restrict__ xin,
                                                  const float* __restrict__ adj,
                                                  const float* __restrict__ W,
                                                  float* __restrict__ xout) {
    __shared__ float yds[FOUT * N];
    const int b  = (int)(blockIdx.x >> 6);
    const int n0 = (int)(blockIdx.x & 63) << 4;
    y_phase<FIN, FOUT>(xin, W, yds, b);
    __syncthreads();
    adj_rows_tanh_write<FOUT>(adj + (size_t)b * N * N, yds,
                              xout + (size_t)b * FOUT * N, n0);
}

// ---------------------------------------------------------------------------
// Generic bf16-adj layer kernel. [HW-verified r10, layers 2-5]
// ---------------------------------------------------------------------------
template <int FIN, int FOUT>
__global__ __launch_bounds__(256, 4) void layer_bf_k(const float* __restrict__ xin,
                                                     const unsigned short* __restrict__ adjbf,
                                                     const float* __restrict__ W,
                                                     float* __restrict__ xout) {
    __shared__ float yds[FOUT * N];
    const int b  = (int)(blockIdx.x >> 6);
    const int n0 = (int)(blockIdx.x & 63) << 4;
    y_phase<FIN, FOUT>(xin, W, yds, b);
    __syncthreads();

    const int wave = (int)(threadIdx.x >> 6);
    const int lane = (int)(threadIdx.x & 63);
    const int nb   = n0 + (wave << 2);
    const unsigned short* ab = adjbf + ((size_t)b << 20);
    float* xoutb = xout + (size_t)b * FOUT * N;

    float v[32];
#pragma unroll
    for (int i = 0; i < 32; ++i) v[i] = 0.f;
#pragma unroll
    for (int k = 0; k < 4; ++k) {
        const int m = (k << 8) + (lane << 2);
        float4 a4[4];
#pragma unroll
        for (int r = 0; r < 4; ++r) {
            const ushort4 raw = *(const ushort4*)(ab + (((size_t)(nb + r)) << 10) + m);
            a4[r].x = bf2f(raw.x); a4[r].y = bf2f(raw.y);
            a4[r].z = bf2f(raw.z); a4[r].w = bf2f(raw.w);
        }
#pragma unroll
        for (int f = 0; f < FOUT; ++f) {
            const float4 yv = *(const float4*)&yds[f * N + m];
#pragma unroll
            for (int r = 0; r < 4; ++r)
                v[r * 8 + f] += a4[r].x * yv.x + a4[r].y * yv.y +
                                a4[r].z * yv.z + a4[r].w * yv.w;
        }
    }
    const float tot = reduce32(v);
    const int s = rev5(lane & 31);
    const int r = s >> 3, f = s & 7;
    if (lane < 32 && f < FOUT)
        xoutb[(size_t)f * N + nb + r] = tanhf(tot);
}

// ---------------------------------------------------------------------------
// Layer 1: reads X [B][N][8] directly; optionally emits bf16 copy of adj.
// [HW-verified r10]
// ---------------------------------------------------------------------------
template <bool STORE_BF>
__global__ __launch_bounds__(256, 4) void layer1_k(const float* __restrict__ X,
                                                   const float* __restrict__ adj,
                                                   const float* __restrict__ W,
                                                   float* __restrict__ xout,
                                                   unsigned short* __restrict__ adjbf) {
    __shared__ float yds[7 * N];
    const int b  = (int)(blockIdx.x >> 6);
    const int n0 = (int)(blockIdx.x & 63) << 4;

    float w[8][7];
#pragma unroll
    for (int fi = 0; fi < 8; ++fi)
#pragma unroll
        for (int f = 0; f < 7; ++f) w[fi][f] = W[fi * 7 + f];

    {
        const int m4 = (int)(threadIdx.x << 2);
        const float* xp = X + (size_t)b * 8192 + (size_t)m4 * 8;
        float4 lo[4], hi[4];
#pragma unroll
        for (int j = 0; j < 4; ++j) {
            lo[j] = *(const float4*)(xp + j * 8);
            hi[j] = *(const float4*)(xp + j * 8 + 4);
        }
#pragma unroll
        for (int f = 0; f < 7; ++f) {
            float4 a;
            a.x = lo[0].x * w[0][f] + lo[0].y * w[1][f] + lo[0].z * w[2][f] + lo[0].w * w[3][f]
                + hi[0].x * w[4][f] + hi[0].y * w[5][f] + hi[0].z * w[6][f] + hi[0].w * w[7][f];
            a.y = lo[1].x * w[0][f] + lo[1].y * w[1][f] + lo[1].z * w[2][f] + lo[1].w * w[3][f]
                + hi[1].x * w[4][f] + hi[1].y * w[5][f] + hi[1].z * w[6][f] + hi[1].w * w[7][f];
            a.z = lo[2].x * w[0][f] + lo[2].y * w[1][f] + lo[2].z * w[2][f] + lo[2].w * w[3][f]
                + hi[2].x * w[4][f] + hi[2].y * w[5][f] + hi[2].z * w[6][f] + hi[2].w * w[7][f];
            a.w = lo[3].x * w[0][f] + lo[3].y * w[1][f] + lo[3].z * w[2][f] + lo[3].w * w[3][f]
                + hi[3].x * w[4][f] + hi[3].y * w[5][f] + hi[3].z * w[6][f] + hi[3].w * w[7][f];
            *(float4*)&yds[f * N + m4] = a;
        }
    }
    __syncthreads();

    {
        const int wave = (int)(threadIdx.x >> 6);
        const int lane = (int)(threadIdx.x & 63);
        const int nb   = n0 + (wave << 2);
        const float* adjb = adj + (size_t)b * N * N;
        unsigned short* ab = adjbf + ((size_t)b << 20);
        float* xoutb = xout + (size_t)b * 7 * N;

        float v[32];
#pragma unroll
        for (int i = 0; i < 32; ++i) v[i] = 0.f;
#pragma unroll
        for (int k = 0; k < 4; ++k) {
            const int m = (k << 8) + (lane << 2);
            float4 a4[4];
#pragma unroll
            for (int r = 0; r < 4; ++r)
                a4[r] = *(const float4*)(adjb + (size_t)(nb + r) * N + m);
            if (STORE_BF) {
#pragma unroll
                for (int r = 0; r < 4; ++r) {
                    ushort4 s4;
                    s4.x = f2bf(a4[r].x); s4.y = f2bf(a4[r].y);
                    s4.z = f2bf(a4[r].z); s4.w = f2bf(a4[r].w);
                    *(ushort4*)(ab + (((size_t)(nb + r)) << 10) + m) = s4;
                }
            }
#pragma unroll
            for (int f = 0; f < 7; ++f) {
                const float4 yv = *(const float4*)&yds[f * N + m];
#pragma unroll
                for (int r = 0; r < 4; ++r)
                    v[r * 8 + f] += a4[r].x * yv.x + a4[r].y * yv.y +
                                    a4[r].z * yv.z + a4[r].w * yv.w;
            }
        }
        const float tot = reduce32(v);
        const int s = rev5(lane & 31);
        const int r = s >> 3, f = s & 7;
        if (lane < 32 && f < 7)
            xoutb[(size_t)f * N + nb + r] = tanhf(tot);
    }
}

// ---------------------------------------------------------------------------
// mu/lv heads + reparameterization, f32 adj. [HW-verified r9/r10]
// ---------------------------------------------------------------------------
__global__ __launch_bounds__(256, 4) void muvl_k(const float* __restrict__ xin,
                                                 const float* __restrict__ adj,
                                                 const float* __restrict__ eps,
                                                 const float* __restrict__ Wmu,
                                                 const float* __restrict__ Wlv,
                                                 float* __restrict__ out) {
    __shared__ float yds[2 * N];
    const int b  = (int)(blockIdx.x >> 6);
    const int n0 = (int)(blockIdx.x & 63) << 4;

    const float wm0 = Wmu[0], wm1 = Wmu[1];
    const float wl0 = Wlv[0], wl1 = Wlv[1];
    {
        const int m4 = (int)(threadIdx.x << 2);
        const float* xp = xin + (size_t)b * 2 * N;
        float4 x0 = *(const float4*)(xp + m4);
        float4 x1 = *(const float4*)(xp + N + m4);
        float4 ym, yl;
        ym.x = x0.x * wm0 + x1.x * wm1;  ym.y = x0.y * wm0 + x1.y * wm1;
        ym.z = x0.z * wm0 + x1.z * wm1;  ym.w = x0.w * wm0 + x1.w * wm1;
        yl.x = x0.x * wl0 + x1.x * wl1;  yl.y = x0.y * wl0 + x1.y * wl1;
        yl.z = x0.z * wl0 + x1.z * wl1;  yl.w = x0.w * wl0 + x1.w * wl1;
        *(float4*)&yds[m4]     = ym;
        *(float4*)&yds[N + m4] = yl;
    }
    __syncthreads();

    const int wave = (int)(threadIdx.x >> 6);
    const int lane = (int)(threadIdx.x & 63);
    const float* adjb = adj + (size_t)b * N * N;
    const int nb = n0 + (wave << 2);
    float v[32];
#pragma unroll
    for (int i = 0; i < 32; ++i) v[i] = 0.f;
#pragma unroll
    for (int k = 0; k < 4; ++k) {
        const int m = (k << 8) + (lane << 2);
        const float4 ym4 = *(const float4*)&yds[m];
        const float4 yl4 = *(const float4*)&yds[N + m];
#pragma unroll
        for (int r = 0; r < 4; ++r) {
            const float4 a4 = *(const float4*)(adjb + (size_t)(nb + r) * N + m);
            v[r * 8 + 0] += a4.x * ym4.x + a4.y * ym4.y + a4.z * ym4.z + a4.w * ym4.w;
            v[r * 8 + 1] += a4.x * yl4.x + a4.y * yl4.y + a4.z * yl4.z + a4.w * yl4.w;
        }
    }
    const float tot = reduce32(v);
    const float partner = __shfl_xor(tot, 16, 64);
    const int s = rev5(lane & 31);
    if (lane < 32 && (s & 7) == 0) {
        const int r = s >> 3;
        const int n = nb + r;
        const float zm = tot, zlv = partner;
        const float e = eps[b * N + n];
        const float z = zm + e * expf(0.5f * zlv);
        out[b * N + n]         = z;
        out[32768 + b * N + n] = zm;
        out[65536 + b * N + n] = zlv;
    }
}

// ---------------------------------------------------------------------------
// mu/lv heads, bf16 adj variant (error budget: dzlv ~0.005-0.01 ->
// z error 0.25-0.5% << 2% threshold; see r11 analysis).
// ---------------------------------------------------------------------------
__global__ __launch_bounds__(256, 4) void muvl_bf_k(const float* __restrict__ xin,
                                                    const unsigned short* __restrict__ adjbf,
                                                    const float* __restrict__ eps,
                                                    const float* __restrict__ Wmu,
                                                    const float* __restrict__ Wlv,
                                                    float* __restrict__ out) {
    __shared__ float yds[2 * N];
    const int b  = (int)(blockIdx.x >> 6);
    const int n0 = (int)(blockIdx.x & 63) << 4;

    const float wm0 = Wmu[0], wm1 = Wmu[1];
    const float wl0 = Wlv[0], wl1 = Wlv[1];
    {
        const int m4 = (int)(threadIdx.x << 2);
        const float* xp = xin + (size_t)b * 2 * N;
        float4 x0 = *(const float4*)(xp + m4);
        float4 x1 = *(const float4*)(xp + N + m4);
        float4 ym, yl;
        ym.x = x0.x * wm0 + x1.x * wm1;  ym.y = x0.y * wm0 + x1.y * wm1;
        ym.z = x0.z * wm0 + x1.z * wm1;  ym.w = x0.w * wm0 + x1.w * wm1;
        yl.x = x0.x * wl0 + x1.x * wl1;  yl.y = x0.y * wl0 + x1.y * wl1;
        yl.z = x0.z * wl0 + x1.z * wl1;  yl.w = x0.w * wl0 + x1.w * wl1;
        *(float4*)&yds[m4]     = ym;
        *(float4*)&yds[N + m4] = yl;
    }
    __syncthreads();

    const int wave = (int)(threadIdx.x >> 6);
    const int lane = (int)(threadIdx.x & 63);
    const unsigned short* ab = adjbf + ((size_t)b << 20);
    const int nb = n0 + (wave << 2);
    float v[32];
#pragma unroll
    for (int i = 0; i < 32; ++i) v[i] = 0.f;
#pragma unroll
    for (int k = 0; k < 4; ++k) {
        const int m = (k << 8) + (lane << 2);
        const float4 ym4 = *(const float4*)&yds[m];
        const float4 yl4 = *(const float4*)&yds[N + m];
#pragma unroll
        for (int r = 0; r < 4; ++r) {
            const ushort4 raw = *(const ushort4*)(ab + (((size_t)(nb + r)) << 10) + m);
            float4 a4;
            a4.x = bf2f(raw.x); a4.y = bf2f(raw.y);
            a4.z = bf2f(raw.z); a4.w = bf2f(raw.w);
            v[r * 8 + 0] += a4.x * ym4.x + a4.y * ym4.y + a4.z * ym4.z + a4.w * ym4.w;
            v[r * 8 + 1] += a4.x * yl4.x + a4.y * yl4.y + a4.z * yl4.z + a4.w * yl4.w;
        }
    }
    const float tot = reduce32(v);
    const float partner = __shfl_xor(tot, 16, 64);
    const int s = rev5(lane & 31);
    if (lane < 32 && (s & 7) == 0) {
        const int r = s >> 3;
        const int n = nb + r;
        const float zm = tot, zlv = partner;
        const float e = eps[b * N + n];
        const float z = zm + e * expf(0.5f * zlv);
        out[b * N + n]         = z;
        out[32768 + b * N + n] = zm;
        out[65536 + b * N + n] = zlv;
    }
}

// ---------------------------------------------------------------------------
// adj_pred[b][n][m] = z[b][n] * z[b][m]  [HW-verified r1/r9/r10]
// ---------------------------------------------------------------------------
__global__ __launch_bounds__(256) void adjpred_k(const float* __restrict__ z,
                                                 float* __restrict__ out) {
    const int b = blockIdx.x >> 10;
    const int n = blockIdx.x & 1023;
    const float zn = z[b * N + n];
    const int m4 = threadIdx.x << 2;
    const float4 zm4 = *(const float4*)(z + b * N + m4);
    float4 o;
    o.x = zn * zm4.x; o.y = zn * zm4.y; o.z = zn * zm4.z; o.w = zn * zm4.w;
    *(float4*)(out + ((size_t)b << 20) + ((size_t)n << 10) + m4) = o;
}

// ---------------------------------------------------------------------------
extern "C" void kernel_launch(void* const* d_in, const int* in_sizes, int n_in,
                              void* d_out, int out_size, void* d_ws, size_t ws_size,
                              hipStream_t stream) {
    const float* X   = (const float*)d_in[0];
    const float* adj = (const float*)d_in[1];
    const float* eps = (const float*)d_in[2];
    const float* W0  = (const float*)d_in[3];
    const float* W1  = (const float*)d_in[4];
    const float* W2  = (const float*)d_in[5];
    const float* W3  = (const float*)d_in[6];
    const float* W4  = (const float*)d_in[7];
    const float* W5  = (const float*)d_in[8];
    const float* Wmu = (const float*)d_in[9];
    const float* Wlv = (const float*)d_in[10];

    float* out  = (float*)d_out;
    float* bufA = (float*)d_ws;                  // [B][7][N] ping
    float* bufB = bufA + (size_t)7 * B * N;      // [B][7][N] pong
    unsigned short* adjbf = (unsigned short*)(bufB + (size_t)7 * B * N);

    const size_t need = (size_t)14 * B * N * sizeof(float)
                      + (size_t)B * N * N * sizeof(unsigned short);

    if (ws_size >= need) {
        // bf16-adj path: f32 adj read exactly once (layer1, which also emits
        // the bf16 copy); every subsequent adj pass reads bf16 (67MB).
        layer1_k<true>  <<<2048, 256, 0, stream>>>(X, adj, W0, bufA, adjbf);
        layer_bf_k<7, 6><<<2048, 256, 0, stream>>>(bufA, adjbf, W1, bufB);
        layer_bf_k<6, 5><<<2048, 256, 0, stream>>>(bufB, adjbf, W2, bufA);
        layer_bf_k<5, 4><<<2048, 256, 0, stream>>>(bufA, adjbf, W3, bufB);
        layer_bf_k<4, 3><<<2048, 256, 0, stream>>>(bufB, adjbf, W4, bufA);
        layer_bf_k<3, 2><<<2048, 256, 0, stream>>>(bufA, adjbf, W5, bufB);
        muvl_bf_k<<<2048, 256, 0, stream>>>(bufB, adjbf, eps, Wmu, Wlv, out);
    } else {
        // Fallback: all-f32 (r9-verified path)
        layer1_k<false> <<<2048, 256, 0, stream>>>(X, adj, W0, bufA, adjbf);
        layer_k<7, 6>   <<<2048, 256, 0, stream>>>(bufA, adj, W1, bufB);
        layer_k<6, 5>   <<<2048, 256, 0, stream>>>(bufB, adj, W2, bufA);
        layer_k<5, 4>   <<<2048, 256, 0, stream>>>(bufA, adj, W3, bufB);
        layer_k<4, 3>   <<<2048, 256, 0, stream>>>(bufB, adj, W4, bufA);
        layer_k<3, 2>   <<<2048, 256, 0, stream>>>(bufA, adj, W5, bufB);
        muvl_k<<<2048, 256, 0, stream>>>(bufB, adj, eps, Wmu, Wlv, out);
    }

    adjpred_k<<<B * N, 256, 0, stream>>>(out, out + 98304);
}